// Round 4
// baseline (268.350 us; speedup 1.0000x reference)
//
#include <hip/hip_runtime.h>

typedef __bf16 bf16;
typedef __bf16 bfx8 __attribute__((ext_vector_type(8)));
typedef __bf16 bfx4 __attribute__((ext_vector_type(4)));
typedef float f32x4 __attribute__((ext_vector_type(4)));

#define MFMA_BF16 __builtin_amdgcn_mfma_f32_16x16x32_bf16

static constexpr int Bq = 4, Sq = 2048, Dq = 1024, Hq = 16, HDq = 64;
static constexpr int Mq = Bq * Sq;          // 8192
static constexpr int D3 = 3 * Dq;           // 3072
static constexpr int NQK = 2 * Dq;          // 2048: Q,K row stride in qkv2
static constexpr float L2E = 1.4426950408889634f;
static constexpr float QSC = 0.125f * L2E;  // softmax scale folded into Q

typedef const __attribute__((address_space(1))) void* gas1;
typedef __attribute__((address_space(3))) void* las3;

__device__ __forceinline__ void gload_lds16(const bf16* g, bf16* l) {
    __builtin_amdgcn_global_load_lds((gas1)g, (las3)l, 16, 0, 0);
}

__device__ __forceinline__ float fast_exp2(float x) {
    return __builtin_amdgcn_exp2f(x);
}

// ---------------- cast x: fp32 -> bf16 ----------------
__global__ __launch_bounds__(256) void cast_f32_bf16(const float* __restrict__ in,
                                                     bf16* __restrict__ out, int n) {
    int i = (blockIdx.x * 256 + threadIdx.x) * 4;
    if (i + 3 < n) {
        float4 v = *(const float4*)(in + i);
        bfx4 r;
        r[0] = (bf16)v.x; r[1] = (bf16)v.y; r[2] = (bf16)v.z; r[3] = (bf16)v.w;
        *(bfx4*)(out + i) = r;
    }
}

// ---------------- transpose+cast: in fp32 [R][C] -> out bf16 [C][R] ----------------
__global__ __launch_bounds__(256) void transpose_cast(const float* __restrict__ in,
                                                      bf16* __restrict__ out, int R, int C) {
    __shared__ float tile[32][33];
    int tx = threadIdx.x, ty = threadIdx.y;     // 32 x 8
    int c0 = blockIdx.x * 32, r0 = blockIdx.y * 32;
    for (int j = 0; j < 32; j += 8)
        tile[ty + j][tx] = in[(size_t)(r0 + ty + j) * C + c0 + tx];
    __syncthreads();
    for (int j = 0; j < 32; j += 8)
        out[(size_t)(c0 + ty + j) * R + r0 + tx] = (bf16)tile[tx][ty + j];
}

// ============ 256x256-tile QKV GEMM, 8-wave (2Mx4N), BK=64, counted-vmcnt pipeline ====
// LDS: 2 dbuf x (A 2half[128][64] + B 2half[128][64]) = 128 KiB, 1 block/CU.
// Per tile t: stage(t+1) issued BEFORE the wait for t -> s_waitcnt vmcnt(8) keeps
// 8 loads in flight across every boundary (T4; never vmcnt(0) in the main loop).
// Race-freedom: each wave's ds_reads are all consumed by its M0..M3 MFMA clusters
// (lgkm drained in program order before the next stage issue), and an explicit
// lgkmcnt(0) before the last pre-MFMA barrier ensures no wave signals that barrier
// with un-serviced LDS reads, so stage-writes (issued only after all waves pass it)
// cannot clobber in-flight reads.
template <int MQ>
__device__ __forceinline__ void lda256(bfx8 (&af)[4][2], const bf16* Ah,
                                       int l16, int quad, int sw) {
    #pragma unroll
    for (int i = 0; i < 4; i++)
        #pragma unroll
        for (int s = 0; s < 2; s++)
            af[i][s] = *(const bfx8*)(Ah + (MQ * 64 + i * 16 + l16) * 64 +
                                      (((s * 4 + quad) ^ sw) * 8));
}
template <int NQ>
__device__ __forceinline__ void ldb256(bfx8 (&bfr)[2][2], const bf16* Bh, int wc1,
                                       int l16, int quad, int sw) {
    #pragma unroll
    for (int j = 0; j < 2; j++)
        #pragma unroll
        for (int s = 0; s < 2; s++)
            bfr[j][s] = *(const bfx8*)(Bh + (wc1 * 64 + (NQ * 2 + j) * 16 + l16) * 64 +
                                       (((s * 4 + quad) ^ sw) * 8));
}
template <int MQ, int NQ>
__device__ __forceinline__ void mma256(f32x4 (&acc)[8][4], const bfx8 (&af)[4][2],
                                       const bfx8 (&bfr)[2][2]) {
    #pragma unroll
    for (int s = 0; s < 2; s++)
        #pragma unroll
        for (int i = 0; i < 4; i++)
            #pragma unroll
            for (int j = 0; j < 2; j++)
                acc[MQ * 4 + i][NQ * 2 + j] =
                    MFMA_BF16(af[i][s], bfr[j][s], acc[MQ * 4 + i][NQ * 2 + j], 0, 0, 0);
}

__device__ __forceinline__ void stage256(const bf16* A, const bf16* Bt, int K,
                                         bf16* Asd, bf16* Bsd, int m0, int n0,
                                         int k0, int tid) {
    #pragma unroll
    for (int L = 0; L < 2; L++) {
        int c = L * 512 + tid;              // 0..1023
        int row = c >> 3;                   // 0..127
        int ch = (c & 7) ^ (row & 7);       // swizzled source chunk
        gload_lds16(A + (size_t)(m0 + row) * K + k0 + ch * 8, Asd + c * 8);
        gload_lds16(A + (size_t)(m0 + 128 + row) * K + k0 + ch * 8, Asd + 8192 + c * 8);
        gload_lds16(Bt + (size_t)(n0 + row) * K + k0 + ch * 8, Bsd + c * 8);
        gload_lds16(Bt + (size_t)(n0 + 128 + row) * K + k0 + ch * 8, Bsd + 8192 + c * 8);
    }
}

__global__ __launch_bounds__(512, 2) void gemm256_qkv(const bf16* __restrict__ A,
                                                      const bf16* __restrict__ Bt,
                                                      bf16* __restrict__ Cqk,
                                                      bf16* __restrict__ Vout) {
    __shared__ bf16 As[2][2 * 8192];
    __shared__ bf16 Bs[2][2 * 8192];
    constexpr int K = Dq, NBX = D3 / 256, NWG = NBX * (Mq / 256);  // 12, 384
    int bid = blockIdx.x;
    int swz = (bid & 7) * (NWG >> 3) + (bid >> 3);   // XCD-chunked, bijective (384%8==0)
    int n0 = (swz % NBX) * 256;
    int m0 = (swz / NBX) * 256;
    int tid = threadIdx.x;
    int lane = tid & 63, wave = tid >> 6;
    int quad = lane >> 4, l16 = lane & 15;
    int wr = wave >> 2, wc = wave & 3;      // 2M x 4N wave grid
    int wc1 = wc & 1;
    int sw = l16 & 7;

    f32x4 acc[8][4] = {};

    stage256(A, Bt, K, &As[0][0], &Bs[0][0], m0, n0, 0, tid);

    #pragma unroll 1
    for (int t = 0; t < 16; t++) {
        if (t < 15) {
            stage256(A, Bt, K, &As[(t + 1) & 1][0], &Bs[(t + 1) & 1][0],
                     m0, n0, (t + 1) * 64, tid);
            asm volatile("s_waitcnt vmcnt(8)" ::: "memory");   // tile t landed; t+1 in flight
        } else {
            asm volatile("s_waitcnt vmcnt(0)" ::: "memory");
        }
        __builtin_amdgcn_s_barrier();
        const bf16* Ah = &As[t & 1][wr * 8192];
        const bf16* Bh = &Bs[t & 1][(wc >> 1) * 8192];
        bfx8 af[4][2], bfr[2][2];
        lda256<0>(af, Ah, l16, quad, sw);
        ldb256<0>(bfr, Bh, wc1, l16, quad, sw);
        __builtin_amdgcn_s_barrier();
        __builtin_amdgcn_s_setprio(1); mma256<0, 0>(acc, af, bfr); __builtin_amdgcn_s_setprio(0);
        ldb256<1>(bfr, Bh, wc1, l16, quad, sw);
        __builtin_amdgcn_s_barrier();
        __builtin_amdgcn_s_setprio(1); mma256<0, 1>(acc, af, bfr); __builtin_amdgcn_s_setprio(0);
        lda256<1>(af, Ah, l16, quad, sw);
        __builtin_amdgcn_s_barrier();
        __builtin_amdgcn_s_setprio(1); mma256<1, 1>(acc, af, bfr); __builtin_amdgcn_s_setprio(0);
        ldb256<0>(bfr, Bh, wc1, l16, quad, sw);
        asm volatile("s_waitcnt lgkmcnt(0)" ::: "memory");  // reads serviced before signaling
        __builtin_amdgcn_s_barrier();
        __builtin_amdgcn_s_setprio(1); mma256<1, 0>(acc, af, bfr); __builtin_amdgcn_s_setprio(0);
    }

    // epilogue: Q,K -> Cqk (stride 2048, Q pre-scaled); V -> Vt transposed+key-permuted
    #pragma unroll
    for (int i = 0; i < 8; i++)
        #pragma unroll
        for (int j = 0; j < 4; j++) {
            int col = n0 + wc * 64 + j * 16 + l16;
            int row0 = m0 + wr * 128 + i * 16 + quad * 4;
            if (col >= NQK) {
                int d = col - NQK;
                int b = row0 >> 11, s0 = row0 & (Sq - 1);
                int w = s0 & 63;
                int sp = (s0 & ~63) | (((w >> 5) * 4 + ((w >> 2) & 3)) * 8) |
                         (((w >> 4) & 1) * 4);
                bfx4 pv;
                #pragma unroll
                for (int r = 0; r < 4; r++) pv[r] = (bf16)acc[i][j][r];
                *(bfx4*)(Vout + ((size_t)b * Dq + d) * Sq + sp) = pv;
            } else {
                float scale = (col < Dq) ? QSC : 1.0f;
                #pragma unroll
                for (int r = 0; r < 4; r++)
                    Cqk[(size_t)(row0 + r) * NQK + col] = (bf16)(acc[i][j][r] * scale);
            }
        }
}

// ---------------- 128-tile GEMM (used for the output projection) ----------------
template <bool OUT_F32>
__global__ __launch_bounds__(256) void gemm_bt(const bf16* __restrict__ A,
                                               const bf16* __restrict__ Bt,
                                               void* __restrict__ Cout,
                                               int M, int N, int K) {
    __shared__ bf16 As[128 * 64];
    __shared__ bf16 Bs[128 * 64];
    int nwg = gridDim.x * gridDim.y;
    int lin = blockIdx.y * gridDim.x + blockIdx.x;
    int swzb = (lin & 7) * (nwg >> 3) + (lin >> 3);   // XCD-chunked (nwg%8==0)
    int m0 = (swzb / gridDim.x) * 128;
    int n0 = (swzb % gridDim.x) * 128;
    int tid = threadIdx.x;
    int lane = tid & 63, wave = tid >> 6;
    int quad = lane >> 4, l16 = lane & 15;
    int wr = wave >> 1, wc = wave & 1;
    int sw = l16 & 7;

    f32x4 acc[4][4] = {};

    for (int k0 = 0; k0 < K; k0 += 64) {
        __syncthreads();
        #pragma unroll
        for (int i = 0; i < 4; i++) {
            int c = i * 256 + tid;
            int row = c >> 3;
            int ch = (c & 7) ^ (row & 7);
            gload_lds16(A + (size_t)(m0 + row) * K + k0 + ch * 8, As + c * 8);
            gload_lds16(Bt + (size_t)(n0 + row) * K + k0 + ch * 8, Bs + c * 8);
        }
        __syncthreads();
        #pragma unroll
        for (int s = 0; s < 2; s++) {
            bfx8 af[4], bfr[4];
            #pragma unroll
            for (int i = 0; i < 4; i++)
                af[i] = *(const bfx8*)(As + (wr * 64 + i * 16 + l16) * 64 +
                                       ((s * 4 + quad) ^ sw) * 8);
            #pragma unroll
            for (int j = 0; j < 4; j++)
                bfr[j] = *(const bfx8*)(Bs + (wc * 64 + j * 16 + l16) * 64 +
                                        ((s * 4 + quad) ^ sw) * 8);
            #pragma unroll
            for (int i = 0; i < 4; i++)
                #pragma unroll
                for (int j = 0; j < 4; j++)
                    acc[i][j] = MFMA_BF16(af[i], bfr[j], acc[i][j], 0, 0, 0);
        }
    }

    #pragma unroll
    for (int i = 0; i < 4; i++)
        #pragma unroll
        for (int j = 0; j < 4; j++) {
            int col = n0 + wc * 64 + j * 16 + l16;
            #pragma unroll
            for (int r = 0; r < 4; r++) {
                int row = m0 + wr * 64 + i * 16 + quad * 4 + r;
                if (OUT_F32)
                    ((float*)Cout)[(size_t)row * N + col] = acc[i][j][r];
                else
                    ((bf16*)Cout)[(size_t)row * N + col] = (bf16)acc[i][j][r];
            }
        }
}

// ---------------- Flash attention: dbuf pipeline, 32KB LDS, in-register P ----------
// 1024 blocks; block = 4 waves; each wave owns 32 q rows (128 q/block).
// bid%8 == head%8 -> all 16 q-blocks of one head on one XCD (K/V L2 reuse).
// P never leaves registers (key-permuted Vt makes the PV B-operand match the
// in-place QK^T output layout).  T5: setprio(1) around MFMA clusters so waves
// in their exp2 phase don't starve other waves' MFMA issue (m191: attn +4-7%).
__global__ __launch_bounds__(256, 4) void attn_kernel(const bf16* __restrict__ qkv,
                                                      const bf16* __restrict__ Vt,
                                                      bf16* __restrict__ out) {
    __shared__ bf16 Ks[2][64 * 64];
    __shared__ bf16 Vs[2][64 * 64];

    int bid = blockIdx.x;
    int qc = (bid >> 3) & 15;                     // q chunk of 128
    int head = ((bid >> 7) << 3) | (bid & 7);     // 0..63; head%8 == bid%8
    int h = head & 15, b = head >> 4;
    int tid = threadIdx.x;
    int lane = tid & 63, wave = tid >> 6;
    int quad = lane >> 4, l16 = lane & 15;
    int sw = l16 & 7;

    size_t base = (size_t)b * Sq * NQK;
    const bf16* Kbase = qkv + base + Dq + h * HDq;
    const bf16* Vbase = Vt + ((size_t)b * Dq + h * HDq) * Sq;
    int q0 = qc * 128 + wave * 32;

    bfx8 qf[2][2];
    #pragma unroll
    for (int qt = 0; qt < 2; qt++)
        #pragma unroll
        for (int s = 0; s < 2; s++)
            qf[qt][s] = *(const bfx8*)(qkv + base + (size_t)(q0 + qt * 16 + l16) * NQK +
                                       h * HDq + s * 32 + quad * 8);

    bfx8 ones;
    #pragma unroll
    for (int j = 0; j < 8; j++) ones[j] = (bf16)1.0f;

    f32x4 oacc[2][4] = {};
    f32x4 lacc[2] = {};

    int c0 = tid, c1 = tid + 256;
    int r0 = c0 >> 3, ch0 = (c0 & 7) ^ (r0 & 7);
    int r1 = c1 >> 3, ch1 = (c1 & 7) ^ (r1 & 7);

    gload_lds16(Kbase + (size_t)r0 * NQK + ch0 * 8, Ks[0] + c0 * 8);
    gload_lds16(Vbase + (size_t)r0 * Sq + ch0 * 8, Vs[0] + c0 * 8);
    gload_lds16(Kbase + (size_t)r1 * NQK + ch1 * 8, Ks[0] + c1 * 8);
    gload_lds16(Vbase + (size_t)r1 * Sq + ch1 * 8, Vs[0] + c1 * 8);

    for (int i = 0; i < 32; i++) {
        int cur = i & 1;
        __syncthreads();
        if (i + 1 < 32) {
            int k0 = (i + 1) * 64;
            bf16* kd = Ks[cur ^ 1];
            bf16* vd = Vs[cur ^ 1];
            gload_lds16(Kbase + (size_t)(k0 + r0) * NQK + ch0 * 8, kd + c0 * 8);
            gload_lds16(Vbase + (size_t)r0 * Sq + k0 + ch0 * 8, vd + c0 * 8);
            gload_lds16(Kbase + (size_t)(k0 + r1) * NQK + ch1 * 8, kd + c1 * 8);
            gload_lds16(Vbase + (size_t)r1 * Sq + k0 + ch1 * 8, vd + c1 * 8);
        }
        const bf16* K_ = Ks[cur];
        const bf16* V_ = Vs[cur];

        #pragma unroll
        for (int hf = 0; hf < 2; hf++) {
            bfx8 kf[2][2];
            #pragma unroll
            for (int tp = 0; tp < 2; tp++) {
                int krow = ((2 * hf + tp) * 16 + l16) * 64;
                kf[tp][0] = *(const bfx8*)(K_ + krow + (quad ^ sw) * 8);
                kf[tp][1] = *(const bfx8*)(K_ + krow + ((4 + quad) ^ sw) * 8);
            }

            bfx8 pf[2];
            #pragma unroll
            for (int qt = 0; qt < 2; qt++) {
                f32x4 s0 = {}, s1 = {};
                __builtin_amdgcn_s_setprio(1);
                s0 = MFMA_BF16(kf[0][0], qf[qt][0], s0, 0, 0, 0);
                s0 = MFMA_BF16(kf[0][1], qf[qt][1], s0, 0, 0, 0);
                s1 = MFMA_BF16(kf[1][0], qf[qt][0], s1, 0, 0, 0);
                s1 = MFMA_BF16(kf[1][1], qf[qt][1], s1, 0, 0, 0);
                __builtin_amdgcn_s_setprio(0);
                bfx8 p;
                #pragma unroll
                for (int r = 0; r < 4; r++) {
                    p[r]     = (bf16)fast_exp2(s0[r]);   // key 4*quad + r
                    p[4 + r] = (bf16)fast_exp2(s1[r]);   // key 16 + 4*quad + r
                }
                pf[qt] = p;
            }

            __builtin_amdgcn_s_setprio(1);
            lacc[0] = MFMA_BF16(pf[0], ones, lacc[0], 0, 0, 0);
            lacc[1] = MFMA_BF16(pf[1], ones, lacc[1], 0, 0, 0);
            #pragma unroll
            for (int nt = 0; nt < 4; nt++) {
                bfx8 vf = *(const bfx8*)(V_ + (nt * 16 + l16) * 64 +
                                         ((hf * 4 + quad) ^ sw) * 8);
                oacc[0][nt] = MFMA_BF16(pf[0], vf, oacc[0][nt], 0, 0, 0);
                oacc[1][nt] = MFMA_BF16(pf[1], vf, oacc[1][nt], 0, 0, 0);
            }
            __builtin_amdgcn_s_setprio(0);
        }
    }

    #pragma unroll
    for (int qt = 0; qt < 2; qt++)
        #pragma unroll
        for (int r = 0; r < 4; r++) {
            int row = q0 + qt * 16 + quad * 4 + r;
            float inv = 1.0f / lacc[qt][r];
            #pragma unroll
            for (int nt = 0; nt < 4; nt++)
                out[((size_t)b * Sq + row) * Dq + h * HDq + nt * 16 + l16] =
                    (bf16)(oacc[qt][nt][r] * inv);
        }
}

extern "C" void kernel_launch(void* const* d_in, const int* in_sizes, int n_in,
                              void* d_out, int out_size, void* d_ws, size_t ws_size,
                              hipStream_t stream) {
    const float* x     = (const float*)d_in[0];
    const float* w_qkv = (const float*)d_in[1];
    const float* w_out = (const float*)d_in[2];
    float* out = (float*)d_out;

    char* ws = (char*)d_ws;
    bf16* x_bf   = (bf16*)ws;                                   // 16 MB (dead after gemm1)
    bf16* wqkvT  = (bf16*)(ws + 16777216);                      //  6 MB
    bf16* woutT  = (bf16*)(ws + 16777216 + 6291456);            //  2 MB
    bf16* qkv2   = (bf16*)(ws + 25165824);                      // 32 MB: Q,K stride 2048
    bf16* Vt     = (bf16*)(ws + 25165824 + 33554432);           // 16 MB: V^T key-permuted
    bf16* attn   = x_bf;   // x_bf dead after gemm1; reuse for attention output

    // 1. casts
    cast_f32_bf16<<<(Mq * Dq) / 4 / 256, 256, 0, stream>>>(x, x_bf, Mq * Dq);
    dim3 tb(32, 8);
    transpose_cast<<<dim3(D3 / 32, Dq / 32), tb, 0, stream>>>(w_qkv, wqkvT, Dq, D3);
    transpose_cast<<<dim3(Dq / 32, Dq / 32), tb, 0, stream>>>(w_out, woutT, Dq, Dq);

    // 2. qkv = x @ w_qkv (256^2 counted-vmcnt pipeline): Q,K -> qkv2, V -> Vt
    gemm256_qkv<<<384, 512, 0, stream>>>(x_bf, wqkvT, qkv2, Vt);

    // 3. attention (1024 blocks, XCD-affine, 32KB LDS)
    attn_kernel<<<1024, 256, 0, stream>>>(qkv2, Vt, attn);

    // 4. out = attn @ w_out  [8192 x 1024], fp32 out
    gemm_bt<true><<<dim3(Dq / 128, Mq / 128), 256, 0, stream>>>(
        attn, woutT, out, Mq, Dq, Dq);
}

// Round 5
// 264.062 us; speedup vs baseline: 1.0162x; 1.0162x over previous
//
#include <hip/hip_runtime.h>

typedef __bf16 bf16;
typedef __bf16 bfx8 __attribute__((ext_vector_type(8)));
typedef __bf16 bfx4 __attribute__((ext_vector_type(4)));
typedef float f32x4 __attribute__((ext_vector_type(4)));

#define MFMA_BF16 __builtin_amdgcn_mfma_f32_16x16x32_bf16

static constexpr int Bq = 4, Sq = 2048, Dq = 1024, Hq = 16, HDq = 64;
static constexpr int Mq = Bq * Sq;          // 8192
static constexpr int D3 = 3 * Dq;           // 3072
static constexpr float L2E = 1.4426950408889634f;
static constexpr float QSC = 0.125f * L2E;  // softmax scale folded into Q

typedef const __attribute__((address_space(1))) void* gas1;
typedef __attribute__((address_space(3))) void* las3;

__device__ __forceinline__ void gload_lds16(const bf16* g, bf16* l) {
    __builtin_amdgcn_global_load_lds((gas1)g, (las3)l, 16, 0, 0);
}

__device__ __forceinline__ float fast_exp2(float x) {
    return __builtin_amdgcn_exp2f(x);
}

// ---------------- cast x: fp32 -> bf16 ----------------
__global__ __launch_bounds__(256) void cast_f32_bf16(const float* __restrict__ in,
                                                     bf16* __restrict__ out, int n) {
    int i = (blockIdx.x * 256 + threadIdx.x) * 4;
    if (i + 3 < n) {
        float4 v = *(const float4*)(in + i);
        bfx4 r;
        r[0] = (bf16)v.x; r[1] = (bf16)v.y; r[2] = (bf16)v.z; r[3] = (bf16)v.w;
        *(bfx4*)(out + i) = r;
    }
}

// ---------------- transpose+cast: in fp32 [R][C] -> out bf16 [C][R] ----------------
__global__ __launch_bounds__(256) void transpose_cast(const float* __restrict__ in,
                                                      bf16* __restrict__ out, int R, int C) {
    __shared__ float tile[32][33];
    int tx = threadIdx.x, ty = threadIdx.y;     // 32 x 8
    int c0 = blockIdx.x * 32, r0 = blockIdx.y * 32;
    for (int j = 0; j < 32; j += 8)
        tile[ty + j][tx] = in[(size_t)(r0 + ty + j) * C + c0 + tx];
    __syncthreads();
    for (int j = 0; j < 32; j += 8)
        out[(size_t)(c0 + ty + j) * R + r0 + tx] = (bf16)tile[tx][ty + j];
}

// ---------------- V transpose: qkv V-part [b][s][hd] -> Vt [b][hd][s'] (bf16) --------
// Output key index PERMUTED within each 64-key group so the attention kernel's b128
// V-fragment read matches the in-register P layout (key = 16*tp + 4*quad + r):
//   output-local o (5 bits, hf=bit5 preserved): source local = 16*((o>>2)&1) + 4*(o>>3) + (o&3).
// Pure LDS-read-index change: global reads and writes stay fully coalesced.
__global__ __launch_bounds__(256) void vtrans(const bf16* __restrict__ qkv,
                                              bf16* __restrict__ Vt) {
    __shared__ bf16 tile[32][33];
    int tx = threadIdx.x, ty = threadIdx.y;     // 32 x 8
    int c0 = blockIdx.x * 32;                   // hd (V column) 0..1023
    int s0 = blockIdx.y * 32;                   // s (32-block; perm stays within it)
    int b = blockIdx.z;
    for (int j = 0; j < 32; j += 8)
        tile[ty + j][tx] = qkv[(size_t)(b * Sq + s0 + ty + j) * D3 + 2 * Dq + c0 + tx];
    int src = 16 * ((tx >> 2) & 1) + 4 * (tx >> 3) + (tx & 3);
    __syncthreads();
    for (int j = 0; j < 32; j += 8)
        Vt[((size_t)b * Dq + c0 + ty + j) * Sq + s0 + tx] = tile[src][ty + j];
}

// ---------------- GEMM: C[M,N] = A[M,K] * Bt[N,K]^T, bf16 in, fp32 acc ----------------
// m97-structure 128^2 tile (measured ~890 TF on this problem) + XCD-chunked block
// swizzle (T1; grid counts are multiples of 8 -> bijective).
template <bool OUT_F32, bool QSCALE>
__global__ __launch_bounds__(256) void gemm_bt(const bf16* __restrict__ A,
                                               const bf16* __restrict__ Bt,
                                               void* __restrict__ Cout,
                                               int M, int N, int K) {
    __shared__ bf16 As[128 * 64];
    __shared__ bf16 Bs[128 * 64];
    int nwg = gridDim.x * gridDim.y;
    int lin = blockIdx.y * gridDim.x + blockIdx.x;
    int swzb = (lin & 7) * (nwg >> 3) + (lin >> 3);   // XCD-chunked (nwg%8==0)
    int m0 = (swzb / gridDim.x) * 128;
    int n0 = (swzb % gridDim.x) * 128;
    int tid = threadIdx.x;
    int lane = tid & 63, wave = tid >> 6;
    int quad = lane >> 4, l16 = lane & 15;
    int wr = wave >> 1, wc = wave & 1;
    int sw = l16 & 7;

    f32x4 acc[4][4] = {};

    for (int k0 = 0; k0 < K; k0 += 64) {
        __syncthreads();
        #pragma unroll
        for (int i = 0; i < 4; i++) {
            int c = i * 256 + tid;          // LDS dest = wave-uniform + lane*16B
            int row = c >> 3;
            int ch = (c & 7) ^ (row & 7);   // swizzled source chunk
            gload_lds16(A + (size_t)(m0 + row) * K + k0 + ch * 8, As + c * 8);
            gload_lds16(Bt + (size_t)(n0 + row) * K + k0 + ch * 8, Bs + c * 8);
        }
        __syncthreads();
        #pragma unroll
        for (int s = 0; s < 2; s++) {
            bfx8 af[4], bfr[4];
            #pragma unroll
            for (int i = 0; i < 4; i++)
                af[i] = *(const bfx8*)(As + (wr * 64 + i * 16 + l16) * 64 +
                                       ((s * 4 + quad) ^ sw) * 8);
            #pragma unroll
            for (int j = 0; j < 4; j++)
                bfr[j] = *(const bfx8*)(Bs + (wc * 64 + j * 16 + l16) * 64 +
                                        ((s * 4 + quad) ^ sw) * 8);
            #pragma unroll
            for (int i = 0; i < 4; i++)
                #pragma unroll
                for (int j = 0; j < 4; j++)
                    acc[i][j] = MFMA_BF16(af[i], bfr[j], acc[i][j], 0, 0, 0);
        }
    }

    #pragma unroll
    for (int i = 0; i < 4; i++)
        #pragma unroll
        for (int j = 0; j < 4; j++) {
            int col = n0 + wc * 64 + j * 16 + l16;
            float scale = (QSCALE && col < Dq) ? QSC : 1.0f;
            #pragma unroll
            for (int r = 0; r < 4; r++) {
                int row = m0 + wr * 64 + i * 16 + quad * 4 + r;
                if (OUT_F32)
                    ((float*)Cout)[(size_t)row * N + col] = acc[i][j][r];
                else
                    ((bf16*)Cout)[(size_t)row * N + col] = (bf16)(acc[i][j][r] * scale);
            }
        }
}

// ---------------- Flash attention: dbuf pipeline, 32KB LDS, in-register P ----------
// 1024 blocks; block = 4 waves; each wave owns 32 q rows (128 q/block).
// bid%8 == head%8 -> all 16 q-blocks of one head on one XCD (K/V L2 reuse).
// P never leaves registers: after swapped QK^T, lane (quad,l16) holds
// key = 16*tp + 4*quad + r for its own q-row l16; Vt is stored key-permuted so the
// natural b128 V-fragment read supplies exactly those keys (zero cross-lane ops,
// zero P-LDS traffic; SQ_LDS_BANK_CONFLICT measured 0).  T5: setprio(1) around
// MFMA clusters (m191: attn +4-7%).
__global__ __launch_bounds__(256, 4) void attn_kernel(const bf16* __restrict__ qkv,
                                                      const bf16* __restrict__ Vt,
                                                      bf16* __restrict__ out) {
    __shared__ bf16 Ks[2][64 * 64];
    __shared__ bf16 Vs[2][64 * 64];

    int bid = blockIdx.x;
    int qc = (bid >> 3) & 15;                     // q chunk of 128
    int head = ((bid >> 7) << 3) | (bid & 7);     // 0..63; head%8 == bid%8
    int h = head & 15, b = head >> 4;
    int tid = threadIdx.x;
    int lane = tid & 63, wave = tid >> 6;
    int quad = lane >> 4, l16 = lane & 15;
    int sw = l16 & 7;

    size_t base = (size_t)b * Sq * D3;
    const bf16* Kbase = qkv + base + Dq + h * HDq;
    const bf16* Vbase = Vt + ((size_t)b * Dq + h * HDq) * Sq;
    int q0 = qc * 128 + wave * 32;

    bfx8 qf[2][2];
    #pragma unroll
    for (int qt = 0; qt < 2; qt++)
        #pragma unroll
        for (int s = 0; s < 2; s++)
            qf[qt][s] = *(const bfx8*)(qkv + base + (size_t)(q0 + qt * 16 + l16) * D3 +
                                       h * HDq + s * 32 + quad * 8);

    bfx8 ones;
    #pragma unroll
    for (int j = 0; j < 8; j++) ones[j] = (bf16)1.0f;

    f32x4 oacc[2][4] = {};
    f32x4 lacc[2] = {};

    int c0 = tid, c1 = tid + 256;
    int r0 = c0 >> 3, ch0 = (c0 & 7) ^ (r0 & 7);
    int r1 = c1 >> 3, ch1 = (c1 & 7) ^ (r1 & 7);

    gload_lds16(Kbase + (size_t)r0 * D3 + ch0 * 8, Ks[0] + c0 * 8);
    gload_lds16(Vbase + (size_t)r0 * Sq + ch0 * 8, Vs[0] + c0 * 8);
    gload_lds16(Kbase + (size_t)r1 * D3 + ch1 * 8, Ks[0] + c1 * 8);
    gload_lds16(Vbase + (size_t)r1 * Sq + ch1 * 8, Vs[0] + c1 * 8);

    for (int i = 0; i < 32; i++) {
        int cur = i & 1;
        __syncthreads();
        if (i + 1 < 32) {
            int k0 = (i + 1) * 64;
            bf16* kd = Ks[cur ^ 1];
            bf16* vd = Vs[cur ^ 1];
            gload_lds16(Kbase + (size_t)(k0 + r0) * D3 + ch0 * 8, kd + c0 * 8);
            gload_lds16(Vbase + (size_t)r0 * Sq + k0 + ch0 * 8, vd + c0 * 8);
            gload_lds16(Kbase + (size_t)(k0 + r1) * D3 + ch1 * 8, kd + c1 * 8);
            gload_lds16(Vbase + (size_t)r1 * Sq + k0 + ch1 * 8, vd + c1 * 8);
        }
        const bf16* K_ = Ks[cur];
        const bf16* V_ = Vs[cur];

        #pragma unroll
        for (int hf = 0; hf < 2; hf++) {
            bfx8 kf[2][2];
            #pragma unroll
            for (int tp = 0; tp < 2; tp++) {
                int krow = ((2 * hf + tp) * 16 + l16) * 64;
                kf[tp][0] = *(const bfx8*)(K_ + krow + (quad ^ sw) * 8);
                kf[tp][1] = *(const bfx8*)(K_ + krow + ((4 + quad) ^ sw) * 8);
            }

            bfx8 pf[2];
            #pragma unroll
            for (int qt = 0; qt < 2; qt++) {
                f32x4 s0 = {}, s1 = {};
                __builtin_amdgcn_s_setprio(1);
                s0 = MFMA_BF16(kf[0][0], qf[qt][0], s0, 0, 0, 0);
                s0 = MFMA_BF16(kf[0][1], qf[qt][1], s0, 0, 0, 0);
                s1 = MFMA_BF16(kf[1][0], qf[qt][0], s1, 0, 0, 0);
                s1 = MFMA_BF16(kf[1][1], qf[qt][1], s1, 0, 0, 0);
                __builtin_amdgcn_s_setprio(0);
                bfx8 p;
                #pragma unroll
                for (int r = 0; r < 4; r++) {
                    p[r]     = (bf16)fast_exp2(s0[r]);   // key 4*quad + r
                    p[4 + r] = (bf16)fast_exp2(s1[r]);   // key 16 + 4*quad + r
                }
                pf[qt] = p;
            }

            __builtin_amdgcn_s_setprio(1);
            lacc[0] = MFMA_BF16(pf[0], ones, lacc[0], 0, 0, 0);
            lacc[1] = MFMA_BF16(pf[1], ones, lacc[1], 0, 0, 0);
            #pragma unroll
            for (int nt = 0; nt < 4; nt++) {
                bfx8 vf = *(const bfx8*)(V_ + (nt * 16 + l16) * 64 +
                                         ((hf * 4 + quad) ^ sw) * 8);
                oacc[0][nt] = MFMA_BF16(pf[0], vf, oacc[0][nt], 0, 0, 0);
                oacc[1][nt] = MFMA_BF16(pf[1], vf, oacc[1][nt], 0, 0, 0);
            }
            __builtin_amdgcn_s_setprio(0);
        }
    }

    #pragma unroll
    for (int qt = 0; qt < 2; qt++)
        #pragma unroll
        for (int r = 0; r < 4; r++) {
            int row = q0 + qt * 16 + quad * 4 + r;
            float inv = 1.0f / lacc[qt][r];
            #pragma unroll
            for (int nt = 0; nt < 4; nt++)
                out[((size_t)b * Sq + row) * Dq + h * HDq + nt * 16 + l16] =
                    (bf16)(oacc[qt][nt][r] * inv);
        }
}

extern "C" void kernel_launch(void* const* d_in, const int* in_sizes, int n_in,
                              void* d_out, int out_size, void* d_ws, size_t ws_size,
                              hipStream_t stream) {
    const float* x     = (const float*)d_in[0];
    const float* w_qkv = (const float*)d_in[1];
    const float* w_out = (const float*)d_in[2];
    float* out = (float*)d_out;

    char* ws = (char*)d_ws;
    bf16* x_bf   = (bf16*)ws;                                   // 16 MB (reused as Vt later)
    bf16* wqkvT  = (bf16*)(ws + 16777216);                      //  6 MB
    bf16* woutT  = (bf16*)(ws + 16777216 + 6291456);            //  2 MB
    bf16* qkv    = (bf16*)(ws + 16777216 + 6291456 + 2097152);  // 48 MB
    bf16* attn   = (bf16*)(ws + 16777216 + 6291456 + 2097152 + 50331648); // 16 MB
    bf16* Vt     = x_bf;   // x_bf dead after gemm1; reuse for V^T (key-permuted)

    // 1. casts
    cast_f32_bf16<<<(Mq * Dq) / 4 / 256, 256, 0, stream>>>(x, x_bf, Mq * Dq);
    dim3 tb(32, 8);
    transpose_cast<<<dim3(D3 / 32, Dq / 32), tb, 0, stream>>>(w_qkv, wqkvT, Dq, D3);
    transpose_cast<<<dim3(Dq / 32, Dq / 32), tb, 0, stream>>>(w_out, woutT, Dq, Dq);

    // 2. qkv = x @ w_qkv   [8192 x 3072], Q columns pre-scaled by 0.125*log2(e)
    gemm_bt<false, true><<<dim3(D3 / 128, Mq / 128), 256, 0, stream>>>(x_bf, wqkvT, qkv, Mq, D3, Dq);

    // 3. V transpose (x_bf dead now), key-permuted for in-register-P attention
    vtrans<<<dim3(Dq / 32, Sq / 32, Bq), tb, 0, stream>>>(qkv, Vt);

    // 4. attention (1024 blocks, XCD-affine, 32KB LDS)
    attn_kernel<<<1024, 256, 0, stream>>>(qkv, Vt, attn);

    // 5. out = attn @ w_out  [8192 x 1024], fp32 out
    gemm_bt<true, false><<<dim3(Dq / 128, Mq / 128), 256, 0, stream>>>(attn, woutT, out, Mq, Dq, Dq);
}

// Round 6
// 252.046 us; speedup vs baseline: 1.0647x; 1.0477x over previous
//
#include <hip/hip_runtime.h>

typedef __bf16 bf16;
typedef __bf16 bfx8 __attribute__((ext_vector_type(8)));
typedef __bf16 bfx4 __attribute__((ext_vector_type(4)));
typedef float f32x4 __attribute__((ext_vector_type(4)));

#define MFMA_BF16 __builtin_amdgcn_mfma_f32_16x16x32_bf16

static constexpr int Bq = 4, Sq = 2048, Dq = 1024, Hq = 16, HDq = 64;
static constexpr int Mq = Bq * Sq;          // 8192
static constexpr int D3 = 3 * Dq;           // 3072
static constexpr int NQK = 2 * Dq;          // 2048: Q,K row stride in qkv2
static constexpr float L2E = 1.4426950408889634f;
static constexpr float QSC = 0.125f * L2E;  // softmax scale folded into Q

typedef const __attribute__((address_space(1))) void* gas1;
typedef __attribute__((address_space(3))) void* las3;

__device__ __forceinline__ void gload_lds16(const bf16* g, bf16* l) {
    __builtin_amdgcn_global_load_lds((gas1)g, (las3)l, 16, 0, 0);
}

__device__ __forceinline__ float fast_exp2(float x) {
    return __builtin_amdgcn_exp2f(x);
}

// ---------------- fused prep: cast x (8192 blocks) + transpose w_qkv (3072) +
// ---------------- transpose w_out (1024) in ONE launch (launch overhead ~10us each)
__global__ __launch_bounds__(256) void prep(const float* __restrict__ x,
                                            const float* __restrict__ w_qkv,
                                            const float* __restrict__ w_out,
                                            bf16* __restrict__ x_bf,
                                            bf16* __restrict__ wqkvT,
                                            bf16* __restrict__ woutT) {
    __shared__ float tile[32][33];
    int bid = blockIdx.x, tid = threadIdx.x;
    if (bid < 8192) {                       // cast x: fp32 -> bf16
        int i = (bid * 256 + tid) * 4;
        float4 v = *(const float4*)(x + i);
        bfx4 r;
        r[0] = (bf16)v.x; r[1] = (bf16)v.y; r[2] = (bf16)v.z; r[3] = (bf16)v.w;
        *(bfx4*)(x_bf + i) = r;
        return;
    }
    const float* in; bf16* out; int R, C, blk;
    if (bid < 8192 + 3072) { blk = bid - 8192;  in = w_qkv; out = wqkvT; R = Dq; C = D3; }
    else                   { blk = bid - 11264; in = w_out; out = woutT; R = Dq; C = Dq; }
    int tx = tid & 31, ty = tid >> 5;       // 32 x 8
    int nbx = C / 32;
    int c0 = (blk % nbx) * 32, r0 = (blk / nbx) * 32;
    for (int j = 0; j < 32; j += 8)
        tile[ty + j][tx] = in[(size_t)(r0 + ty + j) * C + c0 + tx];
    __syncthreads();
    for (int j = 0; j < 32; j += 8)
        out[(size_t)(c0 + ty + j) * R + r0 + tx] = (bf16)tile[tx][ty + j];
}

// swizzled LDS byte offset for the V-transpose epilogue: [128 d][128 s] bf16 tile,
// 16B pair index XORed with (d&15) -> every write/read pattern <=2-way (free, m136)
__device__ __forceinline__ int ldsb(int d, int s) {
    return d * 256 + ((((s >> 3) ^ (d & 15)) << 4) | ((s & 7) * 2));
}

// ---------------- GEMM: C[M,N] = A[M,K] * Bt[N,K]^T, bf16 in, fp32 acc ----------------
// m97-structure 128^2 tile, natural block order (XCD swizzle measured -17.5us here:
// inputs are L3-resident, swizzle only hurts — R0 vs R5 algebra).
// VSPLIT (QKV GEMM): blocks with n0<2048 write Q,K -> Cqk (stride 2048, Q pre-scaled);
//   blocks with n0>=2048 are pure V tiles: epilogue transposes the 128x128 tile through
//   the (now free) 32KB LDS and stores COALESCED 16B runs along s into Vt[b][d][s'],
//   s' key-permuted within each 64-group so the attention kernel's b128 V-fragment read
//   matches the in-register P layout (key = 16*tp + 4*quad + r).  This replaces both
//   the standalone vtrans kernel (launch + 6us) and R3's 8B-scatter epilogue (+17us).
template <bool OUT_F32, bool QSCALE, bool VSPLIT>
__global__ __launch_bounds__(256) void gemm_bt(const bf16* __restrict__ A,
                                               const bf16* __restrict__ Bt,
                                               void* __restrict__ Cout,
                                               bf16* __restrict__ Vout,
                                               int M, int N, int K) {
    __shared__ bf16 smem[2 * 8192];         // As | Bs; reused as 32KB transpose buffer
    bf16* As = smem;
    bf16* Bs = smem + 8192;
    int m0 = blockIdx.y * 128;
    int n0 = blockIdx.x * 128;
    int tid = threadIdx.x;
    int lane = tid & 63, wave = tid >> 6;
    int quad = lane >> 4, l16 = lane & 15;
    int wr = wave >> 1, wc = wave & 1;
    int sw = l16 & 7;

    f32x4 acc[4][4] = {};

    for (int k0 = 0; k0 < K; k0 += 64) {
        __syncthreads();
        #pragma unroll
        for (int i = 0; i < 4; i++) {
            int c = i * 256 + tid;          // LDS dest = wave-uniform + lane*16B
            int row = c >> 3;
            int ch = (c & 7) ^ (row & 7);   // swizzled source chunk
            gload_lds16(A + (size_t)(m0 + row) * K + k0 + ch * 8, As + c * 8);
            gload_lds16(Bt + (size_t)(n0 + row) * K + k0 + ch * 8, Bs + c * 8);
        }
        __syncthreads();
        #pragma unroll
        for (int s = 0; s < 2; s++) {
            bfx8 af[4], bfr[4];
            #pragma unroll
            for (int i = 0; i < 4; i++)
                af[i] = *(const bfx8*)(As + (wr * 64 + i * 16 + l16) * 64 +
                                       ((s * 4 + quad) ^ sw) * 8);
            #pragma unroll
            for (int j = 0; j < 4; j++)
                bfr[j] = *(const bfx8*)(Bs + (wc * 64 + j * 16 + l16) * 64 +
                                        ((s * 4 + quad) ^ sw) * 8);
            #pragma unroll
            for (int i = 0; i < 4; i++)
                #pragma unroll
                for (int j = 0; j < 4; j++)
                    acc[i][j] = MFMA_BF16(af[i], bfr[j], acc[i][j], 0, 0, 0);
        }
    }

    if (VSPLIT && n0 >= NQK) {
        // ---- V tile: acc -> LDS (swizzled [d][s]) -> coalesced key-permuted store
        __syncthreads();                    // all waves done reading As/Bs
        #pragma unroll
        for (int i = 0; i < 4; i++)
            #pragma unroll
            for (int j = 0; j < 4; j++) {
                int d = wc * 64 + j * 16 + l16;
                int s0 = wr * 64 + i * 16 + quad * 4;
                bfx4 pv;
                #pragma unroll
                for (int r = 0; r < 4; r++) pv[r] = (bf16)acc[i][j][r];
                *(bfx4*)((char*)smem + ldsb(d, s0)) = pv;
            }
        __syncthreads();
        int b = m0 >> 11, st = m0 & (Sq - 1), d0 = n0 - NQK;
        // key-perm (verified in R5 vtrans): out[o] = src[32*(o>>5) + 16*((o>>2)&1)
        //                                            + 4*((o>>3)&3) + (o&3)]
        int g = (lane >> 3) & 1, t8 = lane & 7;
        int ss = g * 64 + (t8 >> 2) * 32 + (t8 & 3) * 4;
        #pragma unroll
        for (int rep = 0; rep < 8; rep++) {
            int d = wave * 4 + (lane >> 4) + rep * 16;
            bfx4 lo = *(const bfx4*)((char*)smem + ldsb(d, ss));
            bfx4 hi = *(const bfx4*)((char*)smem + ldsb(d, ss + 16));
            bfx8 o8;
            #pragma unroll
            for (int r = 0; r < 4; r++) { o8[r] = lo[r]; o8[4 + r] = hi[r]; }
            *(bfx8*)(Vout + ((size_t)b * Dq + d0 + d) * Sq + st + g * 64 + t8 * 8) = o8;
        }
        return;
    }

    #pragma unroll
    for (int i = 0; i < 4; i++)
        #pragma unroll
        for (int j = 0; j < 4; j++) {
            int col = n0 + wc * 64 + j * 16 + l16;
            int cstride = VSPLIT ? NQK : N;
            float scale = (QSCALE && col < Dq) ? QSC : 1.0f;
            #pragma unroll
            for (int r = 0; r < 4; r++) {
                int row = m0 + wr * 64 + i * 16 + quad * 4 + r;
                if (OUT_F32)
                    ((float*)Cout)[(size_t)row * cstride + col] = acc[i][j][r];
                else
                    ((bf16*)Cout)[(size_t)row * cstride + col] = (bf16)(acc[i][j][r] * scale);
            }
        }
}

// ---------------- Flash attention: dbuf pipeline, 32KB LDS, in-register P ----------
// 1024 blocks; block = 4 waves; each wave owns 32 q rows (128 q/block).
// bid%8 == head%8 -> all 16 q-blocks of one head on one XCD (K/V L2 reuse).
// P never leaves registers: after swapped QK^T, lane (quad,l16) holds
// key = 16*tp + 4*quad + r for its own q-row l16; Vt is stored key-permuted so the
// natural b128 V-fragment read supplies exactly those keys (zero cross-lane ops,
// zero P-LDS traffic; SQ_LDS_BANK_CONFLICT measured 0; 74.1us, R3-verified).
__global__ __launch_bounds__(256, 4) void attn_kernel(const bf16* __restrict__ qkv,
                                                      const bf16* __restrict__ Vt,
                                                      bf16* __restrict__ out) {
    __shared__ bf16 Ks[2][64 * 64];
    __shared__ bf16 Vs[2][64 * 64];

    int bid = blockIdx.x;
    int qc = (bid >> 3) & 15;                     // q chunk of 128
    int head = ((bid >> 7) << 3) | (bid & 7);     // 0..63; head%8 == bid%8
    int h = head & 15, b = head >> 4;
    int tid = threadIdx.x;
    int lane = tid & 63, wave = tid >> 6;
    int quad = lane >> 4, l16 = lane & 15;
    int sw = l16 & 7;

    size_t base = (size_t)b * Sq * NQK;
    const bf16* Kbase = qkv + base + Dq + h * HDq;
    const bf16* Vbase = Vt + ((size_t)b * Dq + h * HDq) * Sq;
    int q0 = qc * 128 + wave * 32;

    bfx8 qf[2][2];
    #pragma unroll
    for (int qt = 0; qt < 2; qt++)
        #pragma unroll
        for (int s = 0; s < 2; s++)
            qf[qt][s] = *(const bfx8*)(qkv + base + (size_t)(q0 + qt * 16 + l16) * NQK +
                                       h * HDq + s * 32 + quad * 8);

    bfx8 ones;
    #pragma unroll
    for (int j = 0; j < 8; j++) ones[j] = (bf16)1.0f;

    f32x4 oacc[2][4] = {};
    f32x4 lacc[2] = {};

    int c0 = tid, c1 = tid + 256;
    int r0 = c0 >> 3, ch0 = (c0 & 7) ^ (r0 & 7);
    int r1 = c1 >> 3, ch1 = (c1 & 7) ^ (r1 & 7);

    gload_lds16(Kbase + (size_t)r0 * NQK + ch0 * 8, Ks[0] + c0 * 8);
    gload_lds16(Vbase + (size_t)r0 * Sq + ch0 * 8, Vs[0] + c0 * 8);
    gload_lds16(Kbase + (size_t)r1 * NQK + ch1 * 8, Ks[0] + c1 * 8);
    gload_lds16(Vbase + (size_t)r1 * Sq + ch1 * 8, Vs[0] + c1 * 8);

    for (int i = 0; i < 32; i++) {
        int cur = i & 1;
        __syncthreads();
        if (i + 1 < 32) {
            int k0 = (i + 1) * 64;
            bf16* kd = Ks[cur ^ 1];
            bf16* vd = Vs[cur ^ 1];
            gload_lds16(Kbase + (size_t)(k0 + r0) * NQK + ch0 * 8, kd + c0 * 8);
            gload_lds16(Vbase + (size_t)r0 * Sq + k0 + ch0 * 8, vd + c0 * 8);
            gload_lds16(Kbase + (size_t)(k0 + r1) * NQK + ch1 * 8, kd + c1 * 8);
            gload_lds16(Vbase + (size_t)r1 * Sq + k0 + ch1 * 8, vd + c1 * 8);
        }
        const bf16* K_ = Ks[cur];
        const bf16* V_ = Vs[cur];

        #pragma unroll
        for (int hf = 0; hf < 2; hf++) {
            bfx8 kf[2][2];
            #pragma unroll
            for (int tp = 0; tp < 2; tp++) {
                int krow = ((2 * hf + tp) * 16 + l16) * 64;
                kf[tp][0] = *(const bfx8*)(K_ + krow + (quad ^ sw) * 8);
                kf[tp][1] = *(const bfx8*)(K_ + krow + ((4 + quad) ^ sw) * 8);
            }

            bfx8 pf[2];
            #pragma unroll
            for (int qt = 0; qt < 2; qt++) {
                f32x4 s0 = {}, s1 = {};
                s0 = MFMA_BF16(kf[0][0], qf[qt][0], s0, 0, 0, 0);
                s0 = MFMA_BF16(kf[0][1], qf[qt][1], s0, 0, 0, 0);
                s1 = MFMA_BF16(kf[1][0], qf[qt][0], s1, 0, 0, 0);
                s1 = MFMA_BF16(kf[1][1], qf[qt][1], s1, 0, 0, 0);
                bfx8 p;
                #pragma unroll
                for (int r = 0; r < 4; r++) {
                    p[r]     = (bf16)fast_exp2(s0[r]);   // key 4*quad + r
                    p[4 + r] = (bf16)fast_exp2(s1[r]);   // key 16 + 4*quad + r
                }
                pf[qt] = p;
                lacc[qt] = MFMA_BF16(pf[qt], ones, lacc[qt], 0, 0, 0);
            }

            #pragma unroll
            for (int nt = 0; nt < 4; nt++) {
                bfx8 vf = *(const bfx8*)(V_ + (nt * 16 + l16) * 64 +
                                         ((hf * 4 + quad) ^ sw) * 8);
                oacc[0][nt] = MFMA_BF16(pf[0], vf, oacc[0][nt], 0, 0, 0);
                oacc[1][nt] = MFMA_BF16(pf[1], vf, oacc[1][nt], 0, 0, 0);
            }
        }
    }

    #pragma unroll
    for (int qt = 0; qt < 2; qt++)
        #pragma unroll
        for (int r = 0; r < 4; r++) {
            int row = q0 + qt * 16 + quad * 4 + r;
            float inv = 1.0f / lacc[qt][r];
            #pragma unroll
            for (int nt = 0; nt < 4; nt++)
                out[((size_t)b * Sq + row) * Dq + h * HDq + nt * 16 + l16] =
                    (bf16)(oacc[qt][nt][r] * inv);
        }
}

extern "C" void kernel_launch(void* const* d_in, const int* in_sizes, int n_in,
                              void* d_out, int out_size, void* d_ws, size_t ws_size,
                              hipStream_t stream) {
    const float* x     = (const float*)d_in[0];
    const float* w_qkv = (const float*)d_in[1];
    const float* w_out = (const float*)d_in[2];
    float* out = (float*)d_out;

    char* ws = (char*)d_ws;
    bf16* x_bf   = (bf16*)ws;                                   // 16 MB (dead after gemm1)
    bf16* wqkvT  = (bf16*)(ws + 16777216);                      //  6 MB
    bf16* woutT  = (bf16*)(ws + 16777216 + 6291456);            //  2 MB
    bf16* qkv2   = (bf16*)(ws + 25165824);                      // 32 MB: Q,K stride 2048
    bf16* Vt     = (bf16*)(ws + 25165824 + 33554432);           // 16 MB: V^T key-permuted
    bf16* attn   = x_bf;   // x_bf dead after gemm1; reuse for attention output

    // 1. prep: cast x + transpose both weights (single launch)
    prep<<<8192 + 3072 + 1024, 256, 0, stream>>>(x, w_qkv, w_out, x_bf, wqkvT, woutT);

    // 2. qkv = x @ w_qkv: Q,K -> qkv2 (Q pre-scaled); V -> Vt via coalesced LDS epilogue
    gemm_bt<false, true, true><<<dim3(D3 / 128, Mq / 128), 256, 0, stream>>>(
        x_bf, wqkvT, qkv2, Vt, Mq, D3, Dq);

    // 3. attention (1024 blocks, XCD-affine, 32KB LDS)
    attn_kernel<<<1024, 256, 0, stream>>>(qkv2, Vt, attn);

    // 4. out = attn @ w_out  [8192 x 1024], fp32 out
    gemm_bt<true, false, false><<<dim3(Dq / 128, Mq / 128), 256, 0, stream>>>(
        attn, woutT, out, nullptr, Mq, Dq, Dq);
}